// Round 1
// baseline (402.567 us; speedup 1.0000x reference)
//
#include <hip/hip_runtime.h>
#include <hip/hip_bf16.h>
#include <cstdint>
#include <cstddef>

#define N_NODES 50000
#define N_EDGES 800000
#define N_POS   200000
#define N_NEG   200000
#define DIM     128
#define NEG_SLOPE 0.2f

__device__ __forceinline__ float wave_max_f(float v) {
#pragma unroll
  for (int o = 32; o > 0; o >>= 1) v = fmaxf(v, __shfl_xor(v, o, 64));
  return v;
}
__device__ __forceinline__ float wave_sum_f(float v) {
#pragma unroll
  for (int o = 32; o > 0; o >>= 1) v += __shfl_xor(v, o, 64);
  return v;
}

// ---------------------------------------------------------------------------
// K1: feat = x @ W.  Block tile 64 rows x 128 cols, K-chunks of 32.
// xs padded pitch 33 (scalar stores/reads, 2-way max bank aliasing = free),
// ws pitch 128 read as float4 (conflict-free with cg = tid>>4 in-wave layout).
// ---------------------------------------------------------------------------
__global__ __launch_bounds__(256) void gemm_feat(
    const float* __restrict__ x, const float* __restrict__ W,
    float* __restrict__ feat, int n)
{
  __shared__ float xs[64][33];
  __shared__ float ws[32][128];
  const int tid = threadIdx.x;
  const int row0 = blockIdx.x * 64;
  const int rg = tid & 15;   // row group: rows rg*4 .. rg*4+3
  const int cg = tid >> 4;   // col group: cols cg*8 .. cg*8+7

  float acc[4][8];
#pragma unroll
  for (int i = 0; i < 4; ++i)
#pragma unroll
    for (int j = 0; j < 8; ++j) acc[i][j] = 0.f;

  for (int kc = 0; kc < DIM; kc += 32) {
    // load x tile: 64 rows x 32 k, 8 floats/thread
    {
      const int r = tid >> 2;
      const int c = (tid & 3) * 8;
      const int grow = row0 + r;
      float4 v0 = make_float4(0.f, 0.f, 0.f, 0.f);
      float4 v1 = make_float4(0.f, 0.f, 0.f, 0.f);
      if (grow < n) {
        const float* src = &x[(size_t)grow * DIM + kc + c];
        v0 = *(const float4*)(src);
        v1 = *(const float4*)(src + 4);
      }
      xs[r][c + 0] = v0.x; xs[r][c + 1] = v0.y; xs[r][c + 2] = v0.z; xs[r][c + 3] = v0.w;
      xs[r][c + 4] = v1.x; xs[r][c + 5] = v1.y; xs[r][c + 6] = v1.z; xs[r][c + 7] = v1.w;
    }
    // load W chunk: 32 k x 128 cols, 16 floats/thread
    {
      const int r = tid >> 3;
      const int c = (tid & 7) * 16;
      const float* src = &W[(size_t)(kc + r) * DIM + c];
      *(float4*)&ws[r][c + 0]  = *(const float4*)(src + 0);
      *(float4*)&ws[r][c + 4]  = *(const float4*)(src + 4);
      *(float4*)&ws[r][c + 8]  = *(const float4*)(src + 8);
      *(float4*)&ws[r][c + 12] = *(const float4*)(src + 12);
    }
    __syncthreads();
#pragma unroll 8
    for (int k = 0; k < 32; ++k) {
      const float a0 = xs[rg * 4 + 0][k];
      const float a1 = xs[rg * 4 + 1][k];
      const float a2 = xs[rg * 4 + 2][k];
      const float a3 = xs[rg * 4 + 3][k];
      const float4 w0 = *(const float4*)&ws[k][cg * 8];
      const float4 w1 = *(const float4*)&ws[k][cg * 8 + 4];
      const float wv[8] = {w0.x, w0.y, w0.z, w0.w, w1.x, w1.y, w1.z, w1.w};
#pragma unroll
      for (int j = 0; j < 8; ++j) {
        acc[0][j] = fmaf(a0, wv[j], acc[0][j]);
        acc[1][j] = fmaf(a1, wv[j], acc[1][j]);
        acc[2][j] = fmaf(a2, wv[j], acc[2][j]);
        acc[3][j] = fmaf(a3, wv[j], acc[3][j]);
      }
    }
    __syncthreads();
  }
#pragma unroll
  for (int i = 0; i < 4; ++i) {
    const int grow = row0 + rg * 4 + i;
    if (grow < n) {
      float4 o0 = make_float4(acc[i][0], acc[i][1], acc[i][2], acc[i][3]);
      float4 o1 = make_float4(acc[i][4], acc[i][5], acc[i][6], acc[i][7]);
      *(float4*)&feat[(size_t)grow * DIM + cg * 8 + 0] = o0;
      *(float4*)&feat[(size_t)grow * DIM + cg * 8 + 4] = o1;
    }
  }
}

// ---------------------------------------------------------------------------
// K2: el[i] = feat[i]·attn_l, er[i] = feat[i]·attn_r.  One wave per node.
// ---------------------------------------------------------------------------
__global__ __launch_bounds__(256) void el_er_kernel(
    const float* __restrict__ feat,
    const float* __restrict__ attn_l, const float* __restrict__ attn_r,
    float* __restrict__ el, float* __restrict__ er, int n)
{
  const int w = (int)((blockIdx.x * blockDim.x + threadIdx.x) >> 6);
  const int lane = threadIdx.x & 63;
  if (w >= n) return;
  const float2 f  = *(const float2*)&feat[(size_t)w * DIM + lane * 2];
  const float2 al = *(const float2*)&attn_l[lane * 2];
  const float2 ar = *(const float2*)&attn_r[lane * 2];
  float pl = f.x * al.x + f.y * al.y;
  float pr = f.x * ar.x + f.y * ar.y;
  pl = wave_sum_f(pl);
  pr = wave_sum_f(pr);
  if (lane == 0) { el[w] = pl; er[w] = pr; }
}

// ---------------------------------------------------------------------------
// CSR build: histogram -> scan -> fill
// ---------------------------------------------------------------------------
__global__ __launch_bounds__(256) void hist_kernel(
    const int* __restrict__ dst, int* __restrict__ counts, int ne)
{
  const int e = blockIdx.x * blockDim.x + threadIdx.x;
  if (e < ne) atomicAdd(&counts[dst[e]], 1);
}

__global__ __launch_bounds__(1024) void scan_kernel(
    const int* __restrict__ counts, int* __restrict__ row_start, int n)
{
  __shared__ int wsum[16];
  __shared__ int carry;
  const int tid = threadIdx.x;
  const int lane = tid & 63;
  const int wvid = tid >> 6;
  if (tid == 0) { carry = 0; row_start[0] = 0; }
  __syncthreads();
  for (int base = 0; base < n; base += 1024) {
    const int i = base + tid;
    int v = (i < n) ? counts[i] : 0;
#pragma unroll
    for (int d = 1; d < 64; d <<= 1) {
      int t = __shfl_up(v, d, 64);
      if (lane >= d) v += t;
    }
    if (lane == 63) wsum[wvid] = v;
    __syncthreads();
    if (tid == 0) {
      int run = carry;
#pragma unroll
      for (int k = 0; k < 16; ++k) { int t = wsum[k]; wsum[k] = run; run += t; }
      carry = run;
    }
    __syncthreads();
    v += wsum[wvid];
    if (i < n) row_start[i + 1] = v;
    __syncthreads();
  }
}

__global__ __launch_bounds__(256) void fill_kernel(
    const int* __restrict__ dst, const int* __restrict__ row_start,
    int* __restrict__ cursor, int* __restrict__ edge_order, int ne)
{
  const int e = blockIdx.x * blockDim.x + threadIdx.x;
  if (e < ne) {
    const int d = dst[e];
    const int p = atomicAdd(&cursor[d], 1);
    edge_order[row_start[d] + p] = e;
  }
}

// ---------------------------------------------------------------------------
// K5: per-dst online softmax + weighted aggregation + bias + relu.
// One wave per destination node; lane owns 2 feature columns.
// ---------------------------------------------------------------------------
__global__ __launch_bounds__(256) void aggregate_kernel(
    const float* __restrict__ feat, const float* __restrict__ el,
    const float* __restrict__ er,
    const int* __restrict__ row_start, const int* __restrict__ edge_order,
    const int* __restrict__ src, const float* __restrict__ bias,
    float* __restrict__ h, int n)
{
  const int wid = (int)((blockIdx.x * blockDim.x + threadIdx.x) >> 6);
  const int lane = threadIdx.x & 63;
  if (wid >= n) return;
  const int beg = row_start[wid];
  const int end = row_start[wid + 1];
  const float ern = er[wid];

  float m = -INFINITY, s = 0.f;
  float ax = 0.f, ay = 0.f;

  for (int cbase = beg; cbase < end; cbase += 64) {
    const int j = cbase + lane;
    const int cnt = min(64, end - cbase);
    int sid = 0;
    float e = -INFINITY;
    if (j < end) {
      const int eidx = edge_order[j];
      sid = src[eidx];
      const float v = el[sid] + ern;
      e = (v > 0.f) ? v : NEG_SLOPE * v;
    }
    const float cm = wave_max_f(e);
    const float nm = fmaxf(m, cm);
    const float scale = __expf(m - nm);  // first chunk: exp(-inf) = 0
    const float w = __expf(e - nm);      // invalid lanes: 0
    s = s * scale + wave_sum_f(w);
    ax *= scale; ay *= scale;
    m = nm;
    for (int t = 0; t < cnt; ++t) {
      const float wt = __shfl(w, t, 64);
      const int st = __shfl(sid, t, 64);
      const float2 f = *(const float2*)&feat[(size_t)st * DIM + lane * 2];
      ax = fmaf(wt, f.x, ax);
      ay = fmaf(wt, f.y, ay);
    }
  }

  const float bx = bias[lane * 2], by = bias[lane * 2 + 1];
  float ox, oy;
  if (end > beg) {
    const float inv = 1.f / s;
    ox = ax * inv + bx;
    oy = ay * inv + by;
  } else {
    ox = bx; oy = by;
  }
  ox = fmaxf(ox, 0.f);
  oy = fmaxf(oy, 0.f);
  *(float2*)&h[(size_t)wid * DIM + lane * 2] = make_float2(ox, oy);
}

// ---------------------------------------------------------------------------
// K6: scores.  One wave per pair; pos pairs then neg pairs.
// ---------------------------------------------------------------------------
__global__ __launch_bounds__(256) void score_kernel(
    const float* __restrict__ h,
    const int* __restrict__ pos_src, const int* __restrict__ pos_dst,
    const int* __restrict__ neg_src, const int* __restrict__ neg_dst,
    float* __restrict__ out, int npos, int nneg)
{
  const int w = (int)((blockIdx.x * blockDim.x + threadIdx.x) >> 6);
  const int lane = threadIdx.x & 63;
  if (w >= npos + nneg) return;
  int a, b;
  if (w < npos) { a = pos_src[w]; b = pos_dst[w]; }
  else          { a = neg_src[w - npos]; b = neg_dst[w - npos]; }
  const float2 fa = *(const float2*)&h[(size_t)a * DIM + lane * 2];
  const float2 fb = *(const float2*)&h[(size_t)b * DIM + lane * 2];
  float p = fa.x * fb.x + fa.y * fb.y;
  p = wave_sum_f(p);
  if (lane == 0) out[w] = p;
}

// ---------------------------------------------------------------------------
extern "C" void kernel_launch(void* const* d_in, const int* in_sizes, int n_in,
                              void* d_out, int out_size, void* d_ws, size_t ws_size,
                              hipStream_t stream) {
  const float* x      = (const float*)d_in[0];
  const float* W      = (const float*)d_in[1];
  const float* attn_l = (const float*)d_in[2];
  const float* attn_r = (const float*)d_in[3];
  const float* bias   = (const float*)d_in[4];
  const int* src      = (const int*)d_in[5];
  const int* dst      = (const int*)d_in[6];
  const int* pos_src  = (const int*)d_in[7];
  const int* pos_dst  = (const int*)d_in[8];
  const int* neg_src  = (const int*)d_in[9];
  const int* neg_dst  = (const int*)d_in[10];
  float* out = (float*)d_out;

  char* ws = (char*)d_ws;
  const size_t FEAT_B = (size_t)N_NODES * DIM * sizeof(float);   // 25.6 MB
  float* feat       = (float*)(ws);
  float* hbuf       = (float*)(ws + FEAT_B);
  float* el         = (float*)(ws + 2 * FEAT_B);
  float* er         = (float*)(ws + 2 * FEAT_B + 200000);
  int*   counts     = (int*)  (ws + 2 * FEAT_B + 400000);
  int*   cursor     = (int*)  (ws + 2 * FEAT_B + 600000);
  int*   row_start  = (int*)  (ws + 2 * FEAT_B + 800000);
  int*   edge_order = (int*)  (ws + 2 * FEAT_B + 1000192);

  hipMemsetAsync(counts, 0, N_NODES * sizeof(int), stream);
  hipMemsetAsync(cursor, 0, N_NODES * sizeof(int), stream);

  gemm_feat<<<(N_NODES + 63) / 64, 256, 0, stream>>>(x, W, feat, N_NODES);
  el_er_kernel<<<(N_NODES + 3) / 4, 256, 0, stream>>>(feat, attn_l, attn_r, el, er, N_NODES);
  hist_kernel<<<(N_EDGES + 255) / 256, 256, 0, stream>>>(dst, counts, N_EDGES);
  scan_kernel<<<1, 1024, 0, stream>>>(counts, row_start, N_NODES);
  fill_kernel<<<(N_EDGES + 255) / 256, 256, 0, stream>>>(dst, row_start, cursor, edge_order, N_EDGES);
  aggregate_kernel<<<(N_NODES + 3) / 4, 256, 0, stream>>>(
      feat, el, er, row_start, edge_order, src, bias, hbuf, N_NODES);
  score_kernel<<<((N_POS + N_NEG) + 3) / 4, 256, 0, stream>>>(
      hbuf, pos_src, pos_dst, neg_src, neg_dst, out, N_POS, N_NEG);
}

// Round 2
// 276.127 us; speedup vs baseline: 1.4579x; 1.4579x over previous
//
#include <hip/hip_runtime.h>
#include <hip/hip_bf16.h>
#include <cstdint>
#include <cstddef>

#define N_NODES 50000
#define N_EDGES 800000
#define N_POS   200000
#define N_NEG   200000
#define DIM     128
#define NEG_SLOPE 0.2f
#define NB_SCAN 49   // ceil(50000/1024)

typedef _Float16 half8 __attribute__((ext_vector_type(8)));

__device__ __forceinline__ float wave_max_f(float v) {
#pragma unroll
  for (int o = 32; o > 0; o >>= 1) v = fmaxf(v, __shfl_xor(v, o, 64));
  return v;
}
__device__ __forceinline__ float wave_sum_f(float v) {
#pragma unroll
  for (int o = 32; o > 0; o >>= 1) v += __shfl_xor(v, o, 64);
  return v;
}

// ---------------------------------------------------------------------------
// K1: feat = x @ W (fp32 compute, fp16 store) + fused el/er epilogue.
// Block tile 64 rows x 128 cols, K-chunks of 32.
// ---------------------------------------------------------------------------
__global__ __launch_bounds__(256) void gemm_feat(
    const float* __restrict__ x, const float* __restrict__ W,
    const float* __restrict__ attn_l, const float* __restrict__ attn_r,
    half8* __restrict__ feat16, float* __restrict__ el, float* __restrict__ er,
    int n)
{
  __shared__ float xs[64][33];
  __shared__ float ws[32][128];
  const int tid = threadIdx.x;
  const int row0 = blockIdx.x * 64;
  const int rg = tid & 15;   // row group: rows rg*4 .. rg*4+3
  const int cg = tid >> 4;   // col group: cols cg*8 .. cg*8+7

  float acc[4][8];
#pragma unroll
  for (int i = 0; i < 4; ++i)
#pragma unroll
    for (int j = 0; j < 8; ++j) acc[i][j] = 0.f;

  for (int kc = 0; kc < DIM; kc += 32) {
    {
      const int r = tid >> 2;
      const int c = (tid & 3) * 8;
      const int grow = row0 + r;
      float4 v0 = make_float4(0.f, 0.f, 0.f, 0.f);
      float4 v1 = make_float4(0.f, 0.f, 0.f, 0.f);
      if (grow < n) {
        const float* srcp = &x[(size_t)grow * DIM + kc + c];
        v0 = *(const float4*)(srcp);
        v1 = *(const float4*)(srcp + 4);
      }
      xs[r][c + 0] = v0.x; xs[r][c + 1] = v0.y; xs[r][c + 2] = v0.z; xs[r][c + 3] = v0.w;
      xs[r][c + 4] = v1.x; xs[r][c + 5] = v1.y; xs[r][c + 6] = v1.z; xs[r][c + 7] = v1.w;
    }
    {
      const int r = tid >> 3;
      const int c = (tid & 7) * 16;
      const float* srcp = &W[(size_t)(kc + r) * DIM + c];
      *(float4*)&ws[r][c + 0]  = *(const float4*)(srcp + 0);
      *(float4*)&ws[r][c + 4]  = *(const float4*)(srcp + 4);
      *(float4*)&ws[r][c + 8]  = *(const float4*)(srcp + 8);
      *(float4*)&ws[r][c + 12] = *(const float4*)(srcp + 12);
    }
    __syncthreads();
#pragma unroll 8
    for (int k = 0; k < 32; ++k) {
      const float a0 = xs[rg * 4 + 0][k];
      const float a1 = xs[rg * 4 + 1][k];
      const float a2 = xs[rg * 4 + 2][k];
      const float a3 = xs[rg * 4 + 3][k];
      const float4 w0 = *(const float4*)&ws[k][cg * 8];
      const float4 w1 = *(const float4*)&ws[k][cg * 8 + 4];
      const float wv[8] = {w0.x, w0.y, w0.z, w0.w, w1.x, w1.y, w1.z, w1.w};
#pragma unroll
      for (int j = 0; j < 8; ++j) {
        acc[0][j] = fmaf(a0, wv[j], acc[0][j]);
        acc[1][j] = fmaf(a1, wv[j], acc[1][j]);
        acc[2][j] = fmaf(a2, wv[j], acc[2][j]);
        acc[3][j] = fmaf(a3, wv[j], acc[3][j]);
      }
    }
    __syncthreads();
  }

  // store feat16 rows
#pragma unroll
  for (int i = 0; i < 4; ++i) {
    const int grow = row0 + rg * 4 + i;
    if (grow < n) {
      half8 o;
#pragma unroll
      for (int j = 0; j < 8; ++j) o[j] = (_Float16)acc[i][j];
      feat16[(size_t)grow * 16 + cg] = o;
    }
  }

  // fused el/er: partial dot per thread, LDS reduce across the 16 col-groups
  const float4 al0 = *(const float4*)&attn_l[cg * 8];
  const float4 al1 = *(const float4*)&attn_l[cg * 8 + 4];
  const float4 ar0 = *(const float4*)&attn_r[cg * 8];
  const float4 ar1 = *(const float4*)&attn_r[cg * 8 + 4];
  const float alv[8] = {al0.x, al0.y, al0.z, al0.w, al1.x, al1.y, al1.z, al1.w};
  const float arv[8] = {ar0.x, ar0.y, ar0.z, ar0.w, ar1.x, ar1.y, ar1.z, ar1.w};
  float* redl = &ws[0][0];            // reuse ws: need 2*64*17 = 2176 <= 4096 floats
  float* redr = redl + 64 * 17;
#pragma unroll
  for (int i = 0; i < 4; ++i) {
    float pl = 0.f, pr = 0.f;
#pragma unroll
    for (int j = 0; j < 8; ++j) {
      pl = fmaf(acc[i][j], alv[j], pl);
      pr = fmaf(acc[i][j], arv[j], pr);
    }
    redl[(rg * 4 + i) * 17 + cg] = pl;
    redr[(rg * 4 + i) * 17 + cg] = pr;
  }
  __syncthreads();
  if (tid < 64) {
    const int grow = row0 + tid;
    if (grow < n) {
      float sl = 0.f, sr = 0.f;
#pragma unroll
      for (int c = 0; c < 16; ++c) {
        sl += redl[tid * 17 + c];
        sr += redr[tid * 17 + c];
      }
      el[grow] = sl;
      er[grow] = sr;
    }
  }
}

// ---------------------------------------------------------------------------
// CSR build: histogram -> 2-level parallel scan -> fill
// ---------------------------------------------------------------------------
__global__ __launch_bounds__(256) void hist_kernel(
    const int* __restrict__ dst, int* __restrict__ counts, int ne)
{
  const int e = blockIdx.x * blockDim.x + threadIdx.x;
  if (e < ne) atomicAdd(&counts[dst[e]], 1);
}

__global__ __launch_bounds__(1024) void scanA_kernel(
    const int* __restrict__ counts, int* __restrict__ excl,
    int* __restrict__ blk_sum, int n)
{
  __shared__ int wsum[16];
  const int tid = threadIdx.x;
  const int lane = tid & 63;
  const int wv = tid >> 6;
  const int i = blockIdx.x * 1024 + tid;
  const int v = (i < n) ? counts[i] : 0;
  int inc = v;
#pragma unroll
  for (int d = 1; d < 64; d <<= 1) {
    int t = __shfl_up(inc, d, 64);
    if (lane >= d) inc += t;
  }
  if (lane == 63) wsum[wv] = inc;
  __syncthreads();
  if (tid == 0) {
    int run = 0;
#pragma unroll
    for (int k = 0; k < 16; ++k) { int t = wsum[k]; wsum[k] = run; run += t; }
    blk_sum[blockIdx.x] = run;
  }
  __syncthreads();
  if (i < n) excl[i] = inc - v + wsum[wv];
}

__global__ __launch_bounds__(64) void scanB_kernel(
    const int* __restrict__ blk_sum, int* __restrict__ blkoff, int nb)
{
  const int t = threadIdx.x;
  const int v = (t < nb) ? blk_sum[t] : 0;
  int inc = v;
#pragma unroll
  for (int d = 1; d < 64; d <<= 1) {
    int u = __shfl_up(inc, d, 64);
    if (t >= d) inc += u;
  }
  if (t < nb) blkoff[t] = inc - v;
}

__global__ __launch_bounds__(256) void fill_kernel(
    const int* __restrict__ dst, const int* __restrict__ excl,
    const int* __restrict__ blkoff, int* __restrict__ cursor,
    int* __restrict__ edge_order, int ne)
{
  const int e = blockIdx.x * blockDim.x + threadIdx.x;
  if (e < ne) {
    const int d = dst[e];
    const int p = atomicAdd(&cursor[d], 1);
    edge_order[excl[d] + blkoff[d >> 10] + p] = e;
  }
}

// ---------------------------------------------------------------------------
// K5: per-dst online softmax + weighted aggregation + bias + relu -> h (fp16).
// One wave per destination node; quarter-wave (16 lanes) per gathered row,
// 4 edges in flight per inner iteration, 16B fp16 loads.
// ---------------------------------------------------------------------------
__global__ __launch_bounds__(256) void aggregate_kernel(
    const half8* __restrict__ feat16, const float* __restrict__ el,
    const float* __restrict__ er,
    const int* __restrict__ excl, const int* __restrict__ blkoff,
    const int* __restrict__ counts,
    const int* __restrict__ edge_order, const int* __restrict__ src,
    const float* __restrict__ bias,
    half8* __restrict__ h16, int n)
{
  const int wid = (int)((blockIdx.x * blockDim.x + threadIdx.x) >> 6);
  const int lane = threadIdx.x & 63;
  const int q = lane >> 4;
  const int ql = lane & 15;
  if (wid >= n) return;
  const int cnt_e = counts[wid];
  const int beg = excl[wid] + blkoff[wid >> 10];
  const int end = beg + cnt_e;
  const float ern = er[wid];

  float m = -INFINITY, s = 0.f;
  float acc[8];
#pragma unroll
  for (int k = 0; k < 8; ++k) acc[k] = 0.f;

  for (int cbase = beg; cbase < end; cbase += 64) {
    const int j = cbase + lane;
    int sid = 0;
    float e = -INFINITY;
    if (j < end) {
      const int eidx = edge_order[j];
      sid = src[eidx];
      const float v = el[sid] + ern;
      e = (v > 0.f) ? v : NEG_SLOPE * v;
    }
    const float cm = wave_max_f(e);
    const float nm = fmaxf(m, cm);
    const float scale = __expf(m - nm);   // first chunk: exp(-inf)=0
    const float w = __expf(e - nm);       // invalid lanes: 0
    s = s * scale + wave_sum_f(w);
#pragma unroll
    for (int k = 0; k < 8; ++k) acc[k] *= scale;
    m = nm;
    const int cc = min(64, end - cbase);
    for (int t = 0; t < cc; t += 4) {
      const int tl = t + q;               // this quarter's edge slot
      const float wt = __shfl(w, tl, 64);
      const int st = __shfl(sid, tl, 64);
      if (tl < cc) {
        const half8 f = feat16[(size_t)st * 16 + ql];
#pragma unroll
        for (int k = 0; k < 8; ++k) acc[k] = fmaf(wt, (float)f[k], acc[k]);
      }
    }
  }

  // combine the 4 quarters (same columns, disjoint edge subsets)
#pragma unroll
  for (int k = 0; k < 8; ++k) {
    acc[k] += __shfl_xor(acc[k], 16, 64);
    acc[k] += __shfl_xor(acc[k], 32, 64);
  }

  const float4 b0 = *(const float4*)&bias[ql * 8];
  const float4 b1 = *(const float4*)&bias[ql * 8 + 4];
  const float bb[8] = {b0.x, b0.y, b0.z, b0.w, b1.x, b1.y, b1.z, b1.w};
  const float inv = (cnt_e > 0) ? 1.f / s : 0.f;
  half8 o;
#pragma unroll
  for (int k = 0; k < 8; ++k) {
    float v = acc[k] * inv + bb[k];
    v = fmaxf(v, 0.f);
    o[k] = (_Float16)v;
  }
  if (q == 0) h16[(size_t)wid * 16 + ql] = o;
}

// ---------------------------------------------------------------------------
// K6: scores. Quarter-wave per pair (4 pairs/wave), fp16 rows, 16B loads.
// ---------------------------------------------------------------------------
__global__ __launch_bounds__(256) void score_kernel(
    const half8* __restrict__ h16,
    const int* __restrict__ pos_src, const int* __restrict__ pos_dst,
    const int* __restrict__ neg_src, const int* __restrict__ neg_dst,
    float* __restrict__ out, int ntot)
{
  const int wid = (int)((blockIdx.x * blockDim.x + threadIdx.x) >> 6);
  const int lane = threadIdx.x & 63;
  const int q = lane >> 4;
  const int ql = lane & 15;
  const int p = wid * 4 + q;
  int a = 0, b = 0;
  if (p < N_POS)      { a = pos_src[p]; b = pos_dst[p]; }
  else if (p < ntot)  { a = neg_src[p - N_POS]; b = neg_dst[p - N_POS]; }
  const half8 ha = h16[(size_t)a * 16 + ql];
  const half8 hb = h16[(size_t)b * 16 + ql];
  float sum = 0.f;
#pragma unroll
  for (int k = 0; k < 8; ++k) sum = fmaf((float)ha[k], (float)hb[k], sum);
#pragma unroll
  for (int o = 8; o > 0; o >>= 1) sum += __shfl_xor(sum, o, 64);
  if (ql == 0 && p < ntot) out[p] = sum;
}

// ---------------------------------------------------------------------------
extern "C" void kernel_launch(void* const* d_in, const int* in_sizes, int n_in,
                              void* d_out, int out_size, void* d_ws, size_t ws_size,
                              hipStream_t stream) {
  const float* x      = (const float*)d_in[0];
  const float* W      = (const float*)d_in[1];
  const float* attn_l = (const float*)d_in[2];
  const float* attn_r = (const float*)d_in[3];
  const float* bias   = (const float*)d_in[4];
  const int* src      = (const int*)d_in[5];
  const int* dst      = (const int*)d_in[6];
  const int* pos_src  = (const int*)d_in[7];
  const int* pos_dst  = (const int*)d_in[8];
  const int* neg_src  = (const int*)d_in[9];
  const int* neg_dst  = (const int*)d_in[10];
  float* out = (float*)d_out;

  char* ws = (char*)d_ws;
  const size_t F16B = (size_t)N_NODES * DIM * sizeof(_Float16);  // 12.8 MB
  half8* feat16     = (half8*)(ws);
  half8* h16        = (half8*)(ws + F16B);
  float* el         = (float*)(ws + 2 * F16B);
  float* er         = (float*)(ws + 2 * F16B + 200000);
  int*   counts     = (int*)  (ws + 2 * F16B + 400000);
  int*   cursor     = (int*)  (ws + 2 * F16B + 600000);   // contiguous with counts
  int*   excl       = (int*)  (ws + 2 * F16B + 800000);
  int*   blkoff     = (int*)  (ws + 2 * F16B + 1000000);
  int*   blk_sum    = (int*)  (ws + 2 * F16B + 1000256);
  int*   edge_order = (int*)  (ws + 2 * F16B + 1000512);

  hipMemsetAsync(counts, 0, 2 * N_NODES * sizeof(int), stream);  // counts+cursor

  gemm_feat<<<(N_NODES + 63) / 64, 256, 0, stream>>>(
      x, W, attn_l, attn_r, feat16, el, er, N_NODES);
  hist_kernel<<<(N_EDGES + 255) / 256, 256, 0, stream>>>(dst, counts, N_EDGES);
  scanA_kernel<<<NB_SCAN, 1024, 0, stream>>>(counts, excl, blk_sum, N_NODES);
  scanB_kernel<<<1, 64, 0, stream>>>(blk_sum, blkoff, NB_SCAN);
  fill_kernel<<<(N_EDGES + 255) / 256, 256, 0, stream>>>(
      dst, excl, blkoff, cursor, edge_order, N_EDGES);
  aggregate_kernel<<<(N_NODES + 3) / 4, 256, 0, stream>>>(
      feat16, el, er, excl, blkoff, counts, edge_order, src, bias, h16, N_NODES);
  score_kernel<<<((N_POS + N_NEG) / 4 + 3) / 4, 256, 0, stream>>>(
      h16, pos_src, pos_dst, neg_src, neg_dst, out, N_POS + N_NEG);
}